// Round 4
// baseline (2388.652 us; speedup 1.0000x reference)
//
#include <hip/hip_runtime.h>
#include <math.h>

#define NT 256
static constexpr int N  = 1024;
static constexpr int NH = 513;
static constexpr int B  = 8;
static constexpr size_t PLANE = (size_t)B * N * NH;   // complex elements per spectral field

__device__ __forceinline__ float2 cmul(float2 a, float2 b){
  return make_float2(a.x*b.x - a.y*b.y, a.x*b.y + a.y*b.x);
}

// ---------------------------------------------------------------------------
// 1024-point complex FFT in LDS, executed by a group of GT threads on its own
// 1024-float2 slice. DIR=1: e^{-i} (forward), DIR=-1: e^{+i} (inverse).
// Unnormalized. __syncthreads() inside is block-wide: ALL groups in a block
// run identical trip counts, so barriers stay uniform.
// ---------------------------------------------------------------------------
template<int DIR, int GT>
__device__ void fftg(float2* s, const float2* __restrict__ tw, int lane){
  for (int i = lane; i < 1024; i += GT){
    int j = (int)(__brev((unsigned)i) >> 22);
    if (j > i){ float2 t = s[i]; s[i] = s[j]; s[j] = t; }
  }
  __syncthreads();
  for (int st = 0; st < 10; ++st){
    int half = 1 << st;
    for (int k = lane; k < 512; k += GT){
      int j  = k & (half - 1);
      int i0 = ((k >> st) << (st + 1)) | j;
      float2 w = tw[j << (9 - st)];          // e^{-2pi i j/len}
      if (DIR < 0) w.y = -w.y;
      float2 a = s[i0];
      float2 t = cmul(w, s[i0 + half]);
      s[i0]        = make_float2(a.x + t.x, a.y + t.y);
      s[i0 + half] = make_float2(a.x - t.x, a.y - t.y);
    }
    __syncthreads();
  }
}

// twiddle table: tw[k] = exp(-2*pi*i*k/1024), k in [0,512)
__global__ __launch_bounds__(256) void init_tw(float2* tw){
  int i = blockIdx.x * 256 + threadIdx.x;
  if (i < 512){
    double ang = -2.0 * M_PI * (double)i / 1024.0;
    tw[i] = make_float2((float)cos(ang), (float)sin(ang));
  }
}

// ---------------------------------------------------------------------------
// Packed row r2c (initial rfft2 of w0): one block does TWO real rows as
// z = a + i*b; unpack A=(Z(k)+conj(Z(-k)))/2, B=-i/2*(Z(k)-conj(Z(-k))).
// Exact for real inputs.
// ---------------------------------------------------------------------------
__global__ __launch_bounds__(NT) void row_r2c_pack(const float* __restrict__ in,
                                                   float2* __restrict__ out,
                                                   const float2* __restrict__ tw){
  __shared__ float2 s[1024];
  const int tid = threadIdx.x;
  size_t pr = blockIdx.x;
  const float* p0 = in + pr * 2048;
  const float* p1 = p0 + 1024;
  for (int i = tid; i < 1024; i += NT) s[i] = make_float2(p0[i], p1[i]);
  __syncthreads();
  fftg<1, NT>(s, tw, tid);
  float2* q0 = out + (size_t)(2 * pr) * NH;
  float2* q1 = q0 + NH;
  for (int k = tid; k < NH; k += NT){
    float2 Zk = s[k];
    float2 Zm = s[(1024 - k) & 1023];
    q0[k] = make_float2(0.5f * (Zk.x + Zm.x), 0.5f * (Zk.y - Zm.y));
    q1[k] = make_float2(0.5f * (Zk.y + Zm.y), 0.5f * (Zm.x - Zk.x));
  }
}

// ---------------------------------------------------------------------------
// Column forward FFT, 8 columns per block (coalesced 64B segments).
// ---------------------------------------------------------------------------
__global__ __launch_bounds__(NT) void col_fwd(const float2* __restrict__ in,
                                              float2* __restrict__ out,
                                              const float2* __restrict__ tw){
  __shared__ float2 s[8][1024];
  const int tid = threadIdx.x;
  int blk = blockIdx.x;                    // b*65 + cblk
  int b = blk / 65, cb = (blk % 65) * 8;
  int c_l = tid & 7, r0 = tid >> 3;
  int cg = min(cb + c_l, 512);
  const float2* p = in + (size_t)b * N * NH + cg;
  for (int i = r0; i < 1024; i += 32) s[c_l][i] = p[(size_t)i * NH];
  __syncthreads();
  int g = tid >> 5, lane = tid & 31;       // FFT groups: 8 x 32 lanes
  fftg<1, 32>(s[g], tw, lane);
  if (cb + c_l < NH){
    float2* q = out + (size_t)b * N * NH + (cb + c_l);
    for (int i = r0; i < 1024; i += 32) q[(size_t)i * NH] = s[c_l][i];
  }
}

// ---------------------------------------------------------------------------
// Per-stage spectral multipliers + inverse column FFT, 4 columns per block.
// Fields: 0: vx_hat = i*(-2pi*ky/lap)*u  1: vy_hat = i*(2pi*kx/lap)*u
//         2: gx_hat = i*(2pi*kx)*u       3: gy_hat = i*(2pi*ky)*u
// T0,T1 live in d_out (dead until finalize); T2,T3 in ws.
// ---------------------------------------------------------------------------
__global__ __launch_bounds__(NT) void spec_col_inv(const float2* __restrict__ u,
                                                   float2* __restrict__ T0,
                                                   float2* __restrict__ T1,
                                                   float2* __restrict__ T2,
                                                   float2* __restrict__ T3,
                                                   const float2* __restrict__ tw){
  __shared__ float2 s[4][1024];
  __shared__ float2 ucol[4][1024];
  const int tid = threadIdx.x;
  int blk = blockIdx.x;                    // b*129 + cblk
  int b = blk / 129, cb = (blk % 129) * 4;
  int c_l = tid & 3, r0 = tid >> 2;
  int cg = min(cb + c_l, 512);
  const float2* p = u + (size_t)b * N * NH + cg;
  for (int i = r0; i < 1024; i += 64) ucol[c_l][i] = p[(size_t)i * NH];
  __syncthreads();
  int g = tid >> 6, lane = tid & 63;       // FFT groups: 4 x 64 lanes
  const float kyf = (float)min(cb + g, 512);
  const float TWO_PI = 6.2831853071795864769f;
  const float FOUR_PI2 = 39.478417604357434f;
  bool zerocol = (cb + g == 0);
  float2* const Ts[4] = {T0, T1, T2, T3};
  for (int f = 0; f < 4; ++f){
    for (int i = lane; i < 1024; i += 64){
      float kxf = (i < 512) ? (float)i : (float)(i - 1024);
      float lap = -FOUR_PI2 * (kxf * kxf + kyf * kyf);
      float lap_safe = (i == 0 && zerocol) ? 1.f : lap;
      float m;
      if      (f == 0) m = -TWO_PI * kyf / lap_safe;
      else if (f == 1) m =  TWO_PI * kxf / lap_safe;
      else if (f == 2) m =  TWO_PI * kxf;
      else             m =  TWO_PI * kyf;
      float2 uv = ucol[g][i];
      s[g][i] = make_float2(-m * uv.y, m * uv.x);
    }
    __syncthreads();
    fftg<-1, 64>(s[g], tw, lane);
    if (cb + c_l < NH){
      float2* q = Ts[f] + (size_t)b * N * NH + (cb + c_l);
      for (int i = r0; i < 1024; i += 64) q[(size_t)i * NH] = s[c_l][i];
    }
    __syncthreads();
  }
}

// ---------------------------------------------------------------------------
// FUSED row stage with Hermitian pair-packing along y.
// CRITICAL: numpy irfft IGNORES the imaginary part of bins ky=0 and ky=512;
// T3 (gy_hat) at ky=512 is purely imaginary and HUGE (2*pi*512*u) -- keeping
// it would leak (-1)^n * Im(T3[.,512]) into the REAL channel of vy at ~300x
// the signal (the round-2 4e9 blowup). Zero Im of bins 0 and 512 on load:
// packed spectra become exactly Hermitian and match numpy semantics.
// ---------------------------------------------------------------------------
__global__ __launch_bounds__(NT) void row_adv_fft(const float2* __restrict__ T0,
                                                  const float2* __restrict__ T1,
                                                  const float2* __restrict__ T2,
                                                  const float2* __restrict__ T3,
                                                  float2* __restrict__ W1,
                                                  const float2* __restrict__ tw){
  __shared__ float2 s[1024];
  __shared__ float prod[1024];
  __shared__ float advr[2][1024];
  const int tid = threadIdx.x;
  int blk = blockIdx.x;                    // b*512 + q
  int b = blk >> 9, q = blk & 511;
  const float inv_n4 = 9.094947017729282e-13f;  // (1/1024^2)^2
  for (int r = 0; r < 2; ++r){
    size_t row_off = ((size_t)b * N + 2 * q + r) * NH;
    for (int pair = 0; pair < 2; ++pair){
      const float2* pa = (pair == 0 ? T0 : T1) + row_off;  // vx / vy
      const float2* pb = (pair == 0 ? T2 : T3) + row_off;  // gx / gy
      for (int i = tid; i < 1024; i += NT){
        float2 A, Bv;
        if (i <= 512){
          A = pa[i]; Bv = pb[i];
          if (i == 0 || i == 512){ A.y = 0.f; Bv.y = 0.f; }  // realify DC/Nyquist
          s[i] = make_float2(A.x - Bv.y, A.y + Bv.x);        // A + iB
        } else {
          int m = 1024 - i; A = pa[m]; Bv = pb[m];
          s[i] = make_float2(A.x + Bv.y, Bv.x - A.y);        // conj(A) + i*conj(B)
        }
      }
      __syncthreads();
      fftg<-1, NT>(s, tw, tid);
      if (pair == 0){
        for (int i = tid; i < 1024; i += NT) prod[i] = s[i].x * s[i].y;
      } else {
        for (int i = tid; i < 1024; i += NT)
          advr[r][i] = -(prod[i] + s[i].x * s[i].y) * inv_n4;
      }
      __syncthreads();
    }
  }
  // packed forward r2c of the two adv rows
  for (int i = tid; i < 1024; i += NT) s[i] = make_float2(advr[0][i], advr[1][i]);
  __syncthreads();
  fftg<1, NT>(s, tw, tid);
  float2* q0 = W1 + ((size_t)b * N + 2 * q) * NH;
  float2* q1 = q0 + NH;
  for (int k = tid; k < NH; k += NT){
    float2 Zk = s[k];
    float2 Zm = s[(1024 - k) & 1023];
    q0[k] = make_float2(0.5f * (Zk.x + Zm.x), 0.5f * (Zk.y - Zm.y));
    q1[k] = make_float2(0.5f * (Zk.y + Zm.y), 0.5f * (Zm.x - Zk.x));
  }
}

// ---------------------------------------------------------------------------
// Column forward FFT of advection spectrum + dealias + h/u CN update.
// Dealias: int(2/3*513) == 342 exactly in double arithmetic (2/3*513 rounds
// UP to 342.0) -> cols c<342 pass. Rows: int(2/3*1024)//2 == 341 -> x<341
// or x>=683 pass.
// ---------------------------------------------------------------------------
__global__ __launch_bounds__(NT) void col_fwd_update(const float2* __restrict__ A,
                                                     float2* __restrict__ u,
                                                     float2* __restrict__ h,
                                                     const float2* __restrict__ tw,
                                                     float gdt, float beta, float mu,
                                                     int first){
  __shared__ float2 s[8][1024];
  const int tid = threadIdx.x;
  int blk = blockIdx.x;                    // b*65 + cblk
  int b = blk / 65, cb = (blk % 65) * 8;
  int c_l = tid & 7, r0 = tid >> 3;
  int cg = min(cb + c_l, 512);
  const float2* p = A + (size_t)b * N * NH + cg;
  for (int i = r0; i < 1024; i += 32) s[c_l][i] = p[(size_t)i * NH];
  __syncthreads();
  int g = tid >> 5, lane = tid & 31;
  fftg<1, 32>(s[g], tw, lane);
  int c = cb + c_l;
  if (c < NH){
    const bool cpass = (c < 342);
    const float kyf = (float)c;
    const float FOUR_PI2 = 39.478417604357434f;
    for (int x = r0; x < 1024; x += 32){
      bool pass = cpass && (x < 341 || x >= 683);
      float2 F = pass ? s[c_l][x] : make_float2(0.f, 0.f);
      size_t off = ((size_t)b * N + x) * NH + c;
      float2 hv;
      if (first) hv = F;
      else { float2 ho = h[off]; hv = make_float2(F.x + beta * ho.x, F.y + beta * ho.y); }
      h[off] = hv;
      float kxf = (x < 512) ? (float)x : (float)(x - 1024);
      float lap = -FOUR_PI2 * (kxf * kxf + kyf * kyf);
      float lin = 1e-3f * lap - 0.1f;               // VISCOSITY*lap - DRAG
      float aa = 1.f + mu * lin;
      float dd = 1.f - mu * lin;
      float2 uv = u[off];
      u[off] = make_float2((uv.x * aa + gdt * hv.x) / dd,
                           (uv.y * aa + gdt * hv.y) / dd);
    }
  }
}

// pack outputs: [u.re, u.im, (u-vort).re/dt, (u-vort).im/dt]
__global__ __launch_bounds__(NT) void finalize(const float2* __restrict__ u,
                                               const float2* __restrict__ vort,
                                               float* __restrict__ out){
  size_t i = (size_t)blockIdx.x * NT + threadIdx.x;
  if (i >= PLANE) return;
  float2 uv = u[i], vv = vort[i];
  float ur = uv.x, ui = uv.y;
  out[i]             = ur;
  out[PLANE + i]     = ui;
  out[2 * PLANE + i] = (ur - vv.x) * 1000.f;   // /dt, dt=1e-3
  out[3 * PLANE + i] = (ui - vv.y) * 1000.f;
}

extern "C" void kernel_launch(void* const* d_in, const int* in_sizes, int n_in,
                              void* d_out, int out_size, void* d_ws, size_t ws_size,
                              hipStream_t stream){
  const float* w0 = (const float*)d_in[0];
  float* out = (float*)d_out;
  char* ws = (char*)d_ws;

  const size_t CB = PLANE * sizeof(float2);       // 33,619,968 bytes
  // ws layout: tw + vort,u,h,W1,T2,T3  => 6*CB + 4KB ~= 202 MB
  size_t off = 0;
  float2* tw   = (float2*)(ws + off); off += 4096;
  float2* vort = (float2*)(ws + off); off += CB;
  float2* u    = (float2*)(ws + off); off += CB;
  float2* h    = (float2*)(ws + off); off += CB;
  float2* W1   = (float2*)(ws + off); off += CB;
  float2* T2   = (float2*)(ws + off); off += CB;
  float2* T3   = (float2*)(ws + off); off += CB;
  // T0, T1 live in d_out (2*CB == out bytes exactly); dead before finalize.
  float2* T0 = (float2*)d_out;
  float2* T1 = (float2*)d_out + PLANE;

  const double ALPHAS[6] = {0.0, 0.1496590219993, 0.3704009573644,
                            0.6222557631345, 0.9582821306748, 1.0};
  const double BETAS[5]  = {0.0, -0.4178904745, -1.192151694643,
                            -1.697784692471, -1.514183444257};
  const double GAMMAS[5] = {0.1496590219993, 0.3792103129999, 0.8229550293869,
                            0.6994504559488, 0.1530572479681};
  const double DT = 1e-3;

  hipLaunchKernelGGL(init_tw, dim3(2), dim3(256), 0, stream, tw);

  // forward rfft2 of w0
  hipLaunchKernelGGL(row_r2c_pack, dim3(B * 512), dim3(NT), 0, stream, w0, W1, tw);
  hipLaunchKernelGGL(col_fwd, dim3(B * 65), dim3(NT), 0, stream, W1, vort, tw);
  hipMemcpyAsync(u, vort, CB, hipMemcpyDeviceToDevice, stream);

  for (int k = 0; k < 5; ++k){
    float gdt  = (float)(GAMMAS[k] * DT);
    float beta = (float)BETAS[k];
    float mu   = (float)(0.5 * DT * (ALPHAS[k + 1] - ALPHAS[k]));
    hipLaunchKernelGGL(spec_col_inv, dim3(B * 129), dim3(NT), 0, stream,
                       u, T0, T1, T2, T3, tw);
    hipLaunchKernelGGL(row_adv_fft, dim3(B * 512), dim3(NT), 0, stream,
                       T0, T1, T2, T3, W1, tw);
    hipLaunchKernelGGL(col_fwd_update, dim3(B * 65), dim3(NT), 0, stream,
                       W1, u, h, tw, gdt, beta, mu, (k == 0) ? 1 : 0);
  }

  hipLaunchKernelGGL(finalize, dim3((int)((PLANE + NT - 1) / NT)), dim3(NT), 0, stream,
                     u, vort, out);
}

// Round 6
// 2311.374 us; speedup vs baseline: 1.0334x; 1.0334x over previous
//
#include <hip/hip_runtime.h>
#include <math.h>

#define NT 256
static constexpr int N  = 1024;
static constexpr int NH = 513;
static constexpr int B  = 8;
static constexpr size_t PLANE = (size_t)B * N * NH;   // complex elements per spectral field

__device__ __forceinline__ float2 cmul(float2 a, float2 b){
  return make_float2(a.x*b.x - a.y*b.y, a.x*b.y + a.y*b.x);
}

// ---------------------------------------------------------------------------
// 1024-point complex FFT in LDS, executed by a group of GT threads on its own
// 1024-float2 slice. DIR=1: e^{-i} (forward), DIR=-1: e^{+i} (inverse).
// Unnormalized. __syncthreads() inside is block-wide: ALL groups in a block
// run identical trip counts, so barriers stay uniform.
// ---------------------------------------------------------------------------
template<int DIR, int GT>
__device__ void fftg(float2* s, const float2* __restrict__ tw, int lane){
  for (int i = lane; i < 1024; i += GT){
    int j = (int)(__brev((unsigned)i) >> 22);
    if (j > i){ float2 t = s[i]; s[i] = s[j]; s[j] = t; }
  }
  __syncthreads();
  for (int st = 0; st < 10; ++st){
    int half = 1 << st;
    for (int k = lane; k < 512; k += GT){
      int j  = k & (half - 1);
      int i0 = ((k >> st) << (st + 1)) | j;
      float2 w = tw[j << (9 - st)];          // e^{-2pi i j/len}
      if (DIR < 0) w.y = -w.y;
      float2 a = s[i0];
      float2 t = cmul(w, s[i0 + half]);
      s[i0]        = make_float2(a.x + t.x, a.y + t.y);
      s[i0 + half] = make_float2(a.x - t.x, a.y - t.y);
    }
    __syncthreads();
  }
}

// twiddle table: tw[k] = exp(-2*pi*i*k/1024), k in [0,512)
__global__ __launch_bounds__(256) void init_tw(float2* tw){
  int i = blockIdx.x * 256 + threadIdx.x;
  if (i < 512){
    double ang = -2.0 * M_PI * (double)i / 1024.0;
    tw[i] = make_float2((float)cos(ang), (float)sin(ang));
  }
}

// ---------------------------------------------------------------------------
// Packed row r2c (initial rfft2 of w0): one block does TWO real rows as
// z = a + i*b; unpack A=(Z(k)+conj(Z(-k)))/2, B=-i/2*(Z(k)-conj(Z(-k))).
// ---------------------------------------------------------------------------
__global__ __launch_bounds__(NT) void row_r2c_pack(const float* __restrict__ in,
                                                   float2* __restrict__ out,
                                                   const float2* __restrict__ tw){
  __shared__ float2 s[1024];
  const int tid = threadIdx.x;
  size_t pr = blockIdx.x;
  const float* p0 = in + pr * 2048;
  const float* p1 = p0 + 1024;
  for (int i = tid; i < 1024; i += NT) s[i] = make_float2(p0[i], p1[i]);
  __syncthreads();
  fftg<1, NT>(s, tw, tid);
  float2* q0 = out + (size_t)(2 * pr) * NH;
  float2* q1 = q0 + NH;
  for (int k = tid; k < NH; k += NT){
    float2 Zk = s[k];
    float2 Zm = s[(1024 - k) & 1023];
    q0[k] = make_float2(0.5f * (Zk.x + Zm.x), 0.5f * (Zk.y - Zm.y));
    q1[k] = make_float2(0.5f * (Zk.y + Zm.y), 0.5f * (Zm.x - Zk.x));
  }
}

// ---------------------------------------------------------------------------
// Column forward FFT, 512 threads, 8 columns/block; writes result to BOTH
// vort and u (replaces the separate d2d memcpy).
// ---------------------------------------------------------------------------
__global__ __launch_bounds__(512, 4) void col_fwd(const float2* __restrict__ in,
                                                  float2* __restrict__ out,
                                                  float2* __restrict__ out2,
                                                  const float2* __restrict__ tw){
  __shared__ float2 s[8][1024];
  const int tid = threadIdx.x;
  int blk = blockIdx.x;                    // b*65 + cblk
  int b = blk / 65, cb = (blk % 65) * 8;
  int c_l = tid & 7, r0 = tid >> 3;        // coalesced mapping (64B segments)
  int cg = min(cb + c_l, 512);
  const float2* p = in + (size_t)b * N * NH + cg;
  #pragma unroll
  for (int k = 0; k < 16; ++k) s[c_l][r0 + 64 * k] = p[(size_t)(r0 + 64 * k) * NH];
  __syncthreads();
  int g = tid >> 6, lane = tid & 63;       // FFT groups: 8 x 64 lanes
  fftg<1, 64>(s[g], tw, lane);
  if (cb + c_l < NH){
    size_t base = (size_t)b * N * NH + (cb + c_l);
    #pragma unroll
    for (int k = 0; k < 16; ++k){
      float2 v = s[c_l][r0 + 64 * k];
      out [base + (size_t)(r0 + 64 * k) * NH] = v;
      out2[base + (size_t)(r0 + 64 * k) * NH] = v;
    }
  }
}

// ---------------------------------------------------------------------------
// Per-stage spectral multipliers + inverse column FFT, 512 threads, 8 cols.
// Fields: 0: vx_hat = i*(-2pi*ky/lap)*u  1: vy_hat = i*(2pi*kx/lap)*u
//         2: gx_hat = i*(2pi*kx)*u       3: gy_hat = i*(2pi*ky)*u
// u's columns are re-read from global per field (L2-resident: 2 blk/CU x
// 64KB x 32 CU = 4MB = one XCD's L2). LDS is only s[8][1024] = 64KB ->
// 16 waves/CU (2x the round-4 occupancy).
// ---------------------------------------------------------------------------
__global__ __launch_bounds__(512, 4) void spec_col_inv(const float2* __restrict__ u,
                                                       float2* __restrict__ T0,
                                                       float2* __restrict__ T1,
                                                       float2* __restrict__ T2,
                                                       float2* __restrict__ T3,
                                                       const float2* __restrict__ tw){
  __shared__ float2 s[8][1024];
  const int tid = threadIdx.x;
  int blk = blockIdx.x;                    // b*65 + cblk
  int b = blk / 65, cb = (blk % 65) * 8;
  int c_l = tid & 7, r0 = tid >> 3;
  int c = cb + c_l;
  int cg = min(c, 512);
  const float2* p = u + (size_t)b * N * NH + cg;
  int g = tid >> 6, lane = tid & 63;
  const float kyc = (float)cg;
  const bool zerocol = (c == 0);
  const float TWO_PI = 6.2831853071795864769f;
  const float FOUR_PI2 = 39.478417604357434f;
  for (int f = 0; f < 4; ++f){
    // load u column (L2-hot after f=0) and apply i*m(kx,ky) in the coalesced mapping
    #pragma unroll
    for (int k = 0; k < 16; ++k){
      int i = r0 + 64 * k;
      float kxf = (i < 512) ? (float)i : (float)(i - 1024);
      float lap = -FOUR_PI2 * (kxf * kxf + kyc * kyc);
      float lap_safe = (i == 0 && zerocol) ? 1.f : lap;
      float m;
      if      (f == 0) m = -TWO_PI * kyc / lap_safe;
      else if (f == 1) m =  TWO_PI * kxf / lap_safe;
      else if (f == 2) m =  TWO_PI * kxf;
      else             m =  TWO_PI * kyc;
      float2 uv = p[(size_t)i * NH];
      s[c_l][i] = make_float2(-m * uv.y, m * uv.x);
    }
    __syncthreads();
    fftg<-1, 64>(s[g], tw, lane);          // ends with __syncthreads()
    float2* q = (f == 0) ? T0 : (f == 1) ? T1 : (f == 2) ? T2 : T3;
    if (c < NH){
      size_t base = (size_t)b * N * NH + c;
      #pragma unroll
      for (int k = 0; k < 16; ++k)
        q[base + (size_t)(r0 + 64 * k) * NH] = s[c_l][r0 + 64 * k];
    }
    __syncthreads();
  }
}

// ---------------------------------------------------------------------------
// FUSED row stage with Hermitian pair-packing along y.
// numpy irfft IGNORES Im of bins ky=0 and ky=512 (gy_hat at ky=512 is purely
// imaginary and HUGE) -> zero Im of those bins on load so the packed spectra
// are exactly Hermitian (this was the round-2 4e9 blowup).
// ---------------------------------------------------------------------------
__global__ __launch_bounds__(NT) void row_adv_fft(const float2* __restrict__ T0,
                                                  const float2* __restrict__ T1,
                                                  const float2* __restrict__ T2,
                                                  const float2* __restrict__ T3,
                                                  float2* __restrict__ W1,
                                                  const float2* __restrict__ tw){
  __shared__ float2 s[1024];
  __shared__ float prod[1024];
  __shared__ float advr[2][1024];
  const int tid = threadIdx.x;
  int blk = blockIdx.x;                    // b*512 + q
  int b = blk >> 9, q = blk & 511;
  const float inv_n4 = 9.094947017729282e-13f;  // (1/1024^2)^2
  for (int r = 0; r < 2; ++r){
    size_t row_off = ((size_t)b * N + 2 * q + r) * NH;
    for (int pair = 0; pair < 2; ++pair){
      const float2* pa = (pair == 0 ? T0 : T1) + row_off;  // vx / vy
      const float2* pb = (pair == 0 ? T2 : T3) + row_off;  // gx / gy
      for (int i = tid; i < 1024; i += NT){
        float2 A, Bv;
        if (i <= 512){
          A = pa[i]; Bv = pb[i];
          if (i == 0 || i == 512){ A.y = 0.f; Bv.y = 0.f; }  // realify DC/Nyquist
          s[i] = make_float2(A.x - Bv.y, A.y + Bv.x);        // A + iB
        } else {
          int m = 1024 - i; A = pa[m]; Bv = pb[m];
          s[i] = make_float2(A.x + Bv.y, Bv.x - A.y);        // conj(A) + i*conj(B)
        }
      }
      __syncthreads();
      fftg<-1, NT>(s, tw, tid);
      if (pair == 0){
        for (int i = tid; i < 1024; i += NT) prod[i] = s[i].x * s[i].y;
      } else {
        for (int i = tid; i < 1024; i += NT)
          advr[r][i] = -(prod[i] + s[i].x * s[i].y) * inv_n4;
      }
      __syncthreads();
    }
  }
  // packed forward r2c of the two adv rows
  for (int i = tid; i < 1024; i += NT) s[i] = make_float2(advr[0][i], advr[1][i]);
  __syncthreads();
  fftg<1, NT>(s, tw, tid);
  float2* q0 = W1 + ((size_t)b * N + 2 * q) * NH;
  float2* q1 = q0 + NH;
  for (int k = tid; k < NH; k += NT){
    float2 Zk = s[k];
    float2 Zm = s[(1024 - k) & 1023];
    q0[k] = make_float2(0.5f * (Zk.x + Zm.x), 0.5f * (Zk.y - Zm.y));
    q1[k] = make_float2(0.5f * (Zk.y + Zm.y), 0.5f * (Zm.x - Zk.x));
  }
}

// ---------------------------------------------------------------------------
// Column forward FFT of advection spectrum + dealias + h/u CN update.
// 512 threads, 8 cols. Dealias: cols c<342 pass (int(2/3*513)==342 exactly);
// rows x<341 or x>=683 pass.
// ---------------------------------------------------------------------------
__global__ __launch_bounds__(512, 4) void col_fwd_update(const float2* __restrict__ A,
                                                         float2* __restrict__ u,
                                                         float2* __restrict__ h,
                                                         const float2* __restrict__ tw,
                                                         float gdt, float beta, float mu,
                                                         int first){
  __shared__ float2 s[8][1024];
  const int tid = threadIdx.x;
  int blk = blockIdx.x;                    // b*65 + cblk
  int b = blk / 65, cb = (blk % 65) * 8;
  int c_l = tid & 7, r0 = tid >> 3;
  int cg = min(cb + c_l, 512);
  const float2* p = A + (size_t)b * N * NH + cg;
  #pragma unroll
  for (int k = 0; k < 16; ++k) s[c_l][r0 + 64 * k] = p[(size_t)(r0 + 64 * k) * NH];
  __syncthreads();
  int g = tid >> 6, lane = tid & 63;
  fftg<1, 64>(s[g], tw, lane);
  int c = cb + c_l;
  if (c < NH){
    const bool cpass = (c < 342);
    const float kyf = (float)c;
    const float FOUR_PI2 = 39.478417604357434f;
    #pragma unroll
    for (int k = 0; k < 16; ++k){
      int x = r0 + 64 * k;
      bool pass = cpass && (x < 341 || x >= 683);
      float2 F = pass ? s[c_l][x] : make_float2(0.f, 0.f);
      size_t off = ((size_t)b * N + x) * NH + c;
      float2 hv;
      if (first) hv = F;
      else { float2 ho = h[off]; hv = make_float2(F.x + beta * ho.x, F.y + beta * ho.y); }
      h[off] = hv;
      float kxf = (x < 512) ? (float)x : (float)(x - 1024);
      float lap = -FOUR_PI2 * (kxf * kxf + kyf * kyf);
      float lin = 1e-3f * lap - 0.1f;               // VISCOSITY*lap - DRAG
      float aa = 1.f + mu * lin;
      float dd = 1.f - mu * lin;
      float2 uv = u[off];
      u[off] = make_float2((uv.x * aa + gdt * hv.x) / dd,
                           (uv.y * aa + gdt * hv.y) / dd);
    }
  }
}

// pack outputs: [u.re, u.im, (u-vort).re/dt, (u-vort).im/dt]
__global__ __launch_bounds__(NT) void finalize(const float2* __restrict__ u,
                                               const float2* __restrict__ vort,
                                               float* __restrict__ out){
  size_t i = (size_t)blockIdx.x * NT + threadIdx.x;
  if (i >= PLANE) return;
  float2 uv = u[i], vv = vort[i];
  float ur = uv.x, ui = uv.y;
  out[i]             = ur;
  out[PLANE + i]     = ui;
  out[2 * PLANE + i] = (ur - vv.x) * 1000.f;   // /dt, dt=1e-3
  out[3 * PLANE + i] = (ui - vv.y) * 1000.f;
}

extern "C" void kernel_launch(void* const* d_in, const int* in_sizes, int n_in,
                              void* d_out, int out_size, void* d_ws, size_t ws_size,
                              hipStream_t stream){
  const float* w0 = (const float*)d_in[0];
  float* out = (float*)d_out;
  char* ws = (char*)d_ws;

  const size_t CB = PLANE * sizeof(float2);       // 33,619,968 bytes
  // ws layout: tw + vort,u,h,W1,T2,T3  => 6*CB + 4KB ~= 202 MB
  size_t off = 0;
  float2* tw   = (float2*)(ws + off); off += 4096;
  float2* vort = (float2*)(ws + off); off += CB;
  float2* u    = (float2*)(ws + off); off += CB;
  float2* h    = (float2*)(ws + off); off += CB;
  float2* W1   = (float2*)(ws + off); off += CB;
  float2* T2   = (float2*)(ws + off); off += CB;
  float2* T3   = (float2*)(ws + off); off += CB;
  // T0, T1 live in d_out (2*CB == out bytes exactly); dead before finalize.
  float2* T0 = (float2*)d_out;
  float2* T1 = (float2*)d_out + PLANE;

  const double ALPHAS[6] = {0.0, 0.1496590219993, 0.3704009573644,
                            0.6222557631345, 0.9582821306748, 1.0};
  const double BETAS[5]  = {0.0, -0.4178904745, -1.192151694643,
                            -1.697784692471, -1.514183444257};
  const double GAMMAS[5] = {0.1496590219993, 0.3792103129999, 0.8229550293869,
                            0.6994504559488, 0.1530572479681};
  const double DT = 1e-3;

  hipLaunchKernelGGL(init_tw, dim3(2), dim3(256), 0, stream, tw);

  // forward rfft2 of w0; col_fwd writes vort AND u (no d2d memcpy)
  hipLaunchKernelGGL(row_r2c_pack, dim3(B * 512), dim3(NT), 0, stream, w0, W1, tw);
  hipLaunchKernelGGL(col_fwd, dim3(B * 65), dim3(512), 0, stream, W1, vort, u, tw);

  for (int k = 0; k < 5; ++k){
    float gdt  = (float)(GAMMAS[k] * DT);
    float beta = (float)BETAS[k];
    float mu   = (float)(0.5 * DT * (ALPHAS[k + 1] - ALPHAS[k]));
    hipLaunchKernelGGL(spec_col_inv, dim3(B * 65), dim3(512), 0, stream,
                       u, T0, T1, T2, T3, tw);
    hipLaunchKernelGGL(row_adv_fft, dim3(B * 512), dim3(NT), 0, stream,
                       T0, T1, T2, T3, W1, tw);
    hipLaunchKernelGGL(col_fwd_update, dim3(B * 65), dim3(512), 0, stream,
                       W1, u, h, tw, gdt, beta, mu, (k == 0) ? 1 : 0);
  }

  hipLaunchKernelGGL(finalize, dim3((int)((PLANE + NT - 1) / NT)), dim3(NT), 0, stream,
                     u, vort, out);
}

// Round 9
// 1381.052 us; speedup vs baseline: 1.7296x; 1.6736x over previous
//
#include <hip/hip_runtime.h>
#include <math.h>

static constexpr int N  = 1024;
static constexpr int NH = 513;        // logical spectral columns
static constexpr int P  = 520;        // padded pitch: 520*8B = 4160B % 64 == 0 (aligned segments)
static constexpr int B  = 8;
static constexpr size_t PPLANE = (size_t)B * N * P;    // padded complex elems per field
static constexpr size_t LPLANE = (size_t)B * N * NH;   // logical complex elems (output layout)
static constexpr int SLOT = 1089;     // per-column LDS stride in float2

__device__ __forceinline__ float2 cmul(float2 a, float2 b){
  return make_float2(a.x*b.x - a.y*b.y, a.x*b.y + a.y*b.x);
}
__device__ __forceinline__ int sw(int e){ return e + (e >> 4); }  // LDS anti-conflict swizzle, max 1086

// ---------------------------------------------------------------------------
// 1024-pt complex FFT in LDS, two radix-2 levels fused per pass (radix-4
// dataflow): 5 passes + bit-reversal = 6 barriers (was 11), half the LDS
// traffic. Data index i lives at LDS slot sw(i). DIR=1 fwd e^{-i}, -1 inverse.
// Block-wide __syncthreads: all groups in a block run identical trip counts.
// Twiddle identity used: tw[k+256] = -i * tw[k].
// ---------------------------------------------------------------------------
template<int DIR, int GT>
__device__ void fftq(float2* s, const float2* __restrict__ tw, int lane){
  for (int i = lane; i < 1024; i += GT){
    int j = (int)(__brev((unsigned)i) >> 22);
    if (j > i){ float2 t = s[sw(i)]; s[sw(i)] = s[sw(j)]; s[sw(j)] = t; }
  }
  __syncthreads();
  #pragma unroll
  for (int st = 0; st < 10; st += 2){
    const int h = 1 << st;
    for (int q = lane; q < 256; q += GT){
      int j  = q & (h - 1);
      int g  = ((q >> st) << (st + 2)) | j;
      int i0 = sw(g), i1 = sw(g + h), i2 = sw(g + 2*h), i3 = sw(g + 3*h);
      float2 A = s[i0], Bv = s[i1], C = s[i2], D = s[i3];
      float2 w1 = tw[j << (9 - st)];
      float2 w2 = tw[j << (8 - st)];
      if (DIR < 0){ w1.y = -w1.y; w2.y = -w2.y; }
      // level st: pairs (A,B) and (C,D), twiddle w1
      float2 t1 = cmul(w1, Bv);
      float2 A1 = make_float2(A.x + t1.x, A.y + t1.y);
      float2 B1 = make_float2(A.x - t1.x, A.y - t1.y);
      float2 t2 = cmul(w1, D);
      float2 C1 = make_float2(C.x + t2.x, C.y + t2.y);
      float2 D1 = make_float2(C.x - t2.x, C.y - t2.y);
      // level st+1: (A1,C1) twiddle w2; (B1,D1) twiddle w3 = -i*w2 (fwd) / +i*conj(w2) (inv)
      float2 t3 = cmul(w2, C1);
      float2 t4c = cmul(w2, D1);
      float2 t4 = (DIR > 0) ? make_float2(t4c.y, -t4c.x) : make_float2(-t4c.y, t4c.x);
      s[i0] = make_float2(A1.x + t3.x, A1.y + t3.y);
      s[i2] = make_float2(A1.x - t3.x, A1.y - t3.y);
      s[i1] = make_float2(B1.x + t4.x, B1.y + t4.y);
      s[i3] = make_float2(B1.x - t4.x, B1.y - t4.y);
    }
    __syncthreads();
  }
}

// twiddle table: tw[k] = exp(-2*pi*i*k/1024), k in [0,512)
__global__ __launch_bounds__(256) void init_tw(float2* tw){
  int i = blockIdx.x * 256 + threadIdx.x;
  if (i < 512){
    double ang = -2.0 * M_PI * (double)i / 1024.0;
    tw[i] = make_float2((float)cos(ang), (float)sin(ang));
  }
}

// ---------------------------------------------------------------------------
// Packed row r2c (initial rfft2 of w0): TWO real rows as z = a + i*b.
// ---------------------------------------------------------------------------
__global__ __launch_bounds__(256) void row_r2c_pack(const float* __restrict__ in,
                                                    float2* __restrict__ out,
                                                    const float2* __restrict__ tw){
  __shared__ float2 s[1088];
  const int tid = threadIdx.x;
  size_t pr = blockIdx.x;
  const float* p0 = in + pr * 2048;
  const float* p1 = p0 + 1024;
  for (int i = tid; i < 1024; i += 256) s[sw(i)] = make_float2(p0[i], p1[i]);
  __syncthreads();
  fftq<1, 256>(s, tw, tid);
  float2* q0 = out + (size_t)(2 * pr) * P;
  float2* q1 = q0 + P;
  for (int k = tid; k < NH; k += 256){
    float2 Zk = s[sw(k)];
    float2 Zm = s[sw((1024 - k) & 1023)];
    q0[k] = make_float2(0.5f * (Zk.x + Zm.x), 0.5f * (Zk.y - Zm.y));
    q1[k] = make_float2(0.5f * (Zk.y + Zm.y), 0.5f * (Zm.x - Zk.x));
  }
}

// ---------------------------------------------------------------------------
// Column forward FFT, 512 thr, 8 cols/block; dual-writes vort and u.
// ---------------------------------------------------------------------------
__global__ __launch_bounds__(512, 4) void col_fwd(const float2* __restrict__ in,
                                                  float2* __restrict__ out,
                                                  float2* __restrict__ out2,
                                                  const float2* __restrict__ tw){
  __shared__ float2 s[8 * SLOT];
  const int tid = threadIdx.x;
  int blk = blockIdx.x;                    // b*65 + cgrp
  int b = blk / 65, cb = (blk % 65) * 8;
  int c_l = tid & 7, r0 = tid >> 3;
  float2* sc = s + c_l * SLOT;
  const float2* p = in + (size_t)b * N * P + (cb + c_l);
  #pragma unroll
  for (int k = 0; k < 16; ++k){ int i = r0 + 64 * k; sc[sw(i)] = p[(size_t)i * P]; }
  __syncthreads();
  int g = tid >> 6, lane = tid & 63;       // 8 groups x 64 lanes
  fftq<1, 64>(s + g * SLOT, tw, lane);
  if (cb + c_l < NH){
    size_t base = (size_t)b * N * P + (cb + c_l);
    #pragma unroll
    for (int k = 0; k < 16; ++k){
      int i = r0 + 64 * k;
      float2 v = sc[sw(i)];
      out [base + (size_t)i * P] = v;
      out2[base + (size_t)i * P] = v;
    }
  }
}

// ---------------------------------------------------------------------------
// Per-stage spectral multiplier + inverse column FFT. ONE FIELD PER BLOCK
// (blockIdx.y = f): 4x more independent blocks, no serial 4-field chain.
// Fields: 0: vx_hat = i*(-2pi*ky/lap)*u   1: vy_hat = i*(2pi*kx/lap)*u
//         2: gx_hat = i*(2pi*kx)*u        3: gy_hat = i*(2pi*ky)*u
// ---------------------------------------------------------------------------
__global__ __launch_bounds__(512, 4) void spec_col_inv(const float2* __restrict__ u,
                                                       float2* __restrict__ T0,
                                                       float2* __restrict__ T1,
                                                       float2* __restrict__ T2,
                                                       float2* __restrict__ T3,
                                                       const float2* __restrict__ tw){
  __shared__ float2 s[8 * SLOT];
  const int tid = threadIdx.x;
  int blk = blockIdx.x;                    // b*65 + cgrp
  int f = blockIdx.y;
  int b = blk / 65, cb = (blk % 65) * 8;
  int c_l = tid & 7, r0 = tid >> 3;
  int c = cb + c_l;
  int cg = min(c, 512);
  float2* sc = s + c_l * SLOT;
  const float2* p = u + (size_t)b * N * P + cg;
  const float kyc = (float)cg;
  const bool zerocol = (c == 0);
  const float TWO_PI = 6.2831853071795864769f;
  const float FOUR_PI2 = 39.478417604357434f;
  #pragma unroll
  for (int k = 0; k < 16; ++k){
    int i = r0 + 64 * k;
    float kxf = (i < 512) ? (float)i : (float)(i - 1024);
    float lap = -FOUR_PI2 * (kxf * kxf + kyc * kyc);
    float lap_safe = (i == 0 && zerocol) ? 1.f : lap;
    float m;
    if      (f == 0) m = -TWO_PI * kyc / lap_safe;
    else if (f == 1) m =  TWO_PI * kxf / lap_safe;
    else if (f == 2) m =  TWO_PI * kxf;
    else             m =  TWO_PI * kyc;
    float2 uv = p[(size_t)i * P];
    sc[sw(i)] = make_float2(-m * uv.y, m * uv.x);
  }
  __syncthreads();
  int g = tid >> 6, lane = tid & 63;
  fftq<-1, 64>(s + g * SLOT, tw, lane);
  float2* q = (f == 0) ? T0 : (f == 1) ? T1 : (f == 2) ? T2 : T3;
  if (c < NH){
    size_t base = (size_t)b * N * P + c;
    #pragma unroll
    for (int k = 0; k < 16; ++k){
      int i = r0 + 64 * k;
      q[base + (size_t)i * P] = sc[sw(i)];
    }
  }
}

// ---------------------------------------------------------------------------
// FUSED row stage, Hermitian pair-packed along y. numpy irfft IGNORES Im of
// bins ky=0 and 512 (gy_hat@512 is purely imaginary & huge) -> zero them so
// packed spectra are exactly Hermitian. Writes W1 (ALIASED to T0: every block
// reads its T0 rows before writing the same W1 rows; rows disjoint across
// blocks -> safe).
// ---------------------------------------------------------------------------
__global__ __launch_bounds__(256) void row_adv_fft(const float2* __restrict__ T0,
                                                   const float2* __restrict__ T1,
                                                   const float2* __restrict__ T2,
                                                   const float2* __restrict__ T3,
                                                   float2* __restrict__ W1,
                                                   const float2* __restrict__ tw){
  __shared__ float2 s[1088];
  __shared__ float prod[1024];
  __shared__ float advr[2][1024];
  const int tid = threadIdx.x;
  int blk = blockIdx.x;                    // b*512 + q
  int b = blk >> 9, qr = blk & 511;
  const float inv_n4 = 9.094947017729282e-13f;  // (1/1024^2)^2
  for (int r = 0; r < 2; ++r){
    size_t row_off = ((size_t)b * N + 2 * qr + r) * P;
    for (int pair = 0; pair < 2; ++pair){
      const float2* pa = (pair == 0 ? T0 : T1) + row_off;  // vx / vy
      const float2* pb = (pair == 0 ? T2 : T3) + row_off;  // gx / gy
      for (int i = tid; i < 1024; i += 256){
        float2 A, Bv;
        if (i <= 512){
          A = pa[i]; Bv = pb[i];
          if (i == 0 || i == 512){ A.y = 0.f; Bv.y = 0.f; }  // realify DC/Nyquist
          s[sw(i)] = make_float2(A.x - Bv.y, A.y + Bv.x);    // A + iB
        } else {
          int m = 1024 - i; A = pa[m]; Bv = pb[m];
          s[sw(i)] = make_float2(A.x + Bv.y, Bv.x - A.y);    // conj(A) + i*conj(B)
        }
      }
      __syncthreads();
      fftq<-1, 256>(s, tw, tid);
      if (pair == 0){
        for (int i = tid; i < 1024; i += 256) prod[i] = s[sw(i)].x * s[sw(i)].y;
      } else {
        for (int i = tid; i < 1024; i += 256)
          advr[r][i] = -(prod[i] + s[sw(i)].x * s[sw(i)].y) * inv_n4;
      }
      __syncthreads();
    }
  }
  // packed forward r2c of the two adv rows
  for (int i = tid; i < 1024; i += 256) s[sw(i)] = make_float2(advr[0][i], advr[1][i]);
  __syncthreads();
  fftq<1, 256>(s, tw, tid);
  float2* q0 = W1 + ((size_t)b * N + 2 * qr) * P;
  float2* q1 = q0 + P;
  for (int k = tid; k < NH; k += 256){
    float2 Zk = s[sw(k)];
    float2 Zm = s[sw((1024 - k) & 1023)];
    q0[k] = make_float2(0.5f * (Zk.x + Zm.x), 0.5f * (Zk.y - Zm.y));
    q1[k] = make_float2(0.5f * (Zk.y + Zm.y), 0.5f * (Zm.x - Zk.x));
  }
}

// ---------------------------------------------------------------------------
// Column forward FFT of advection + dealias + h/u CN update.
// Dealias: cols c<342 pass (int(2/3*513)==342 exactly); rows x<341||x>=683.
// ---------------------------------------------------------------------------
__global__ __launch_bounds__(512, 4) void col_fwd_update(const float2* __restrict__ A,
                                                         float2* __restrict__ u,
                                                         float2* __restrict__ h,
                                                         const float2* __restrict__ tw,
                                                         float gdt, float beta, float mu,
                                                         int first){
  __shared__ float2 s[8 * SLOT];
  const int tid = threadIdx.x;
  int blk = blockIdx.x;                    // b*65 + cgrp
  int b = blk / 65, cb = (blk % 65) * 8;
  int c_l = tid & 7, r0 = tid >> 3;
  float2* sc = s + c_l * SLOT;
  const float2* p = A + (size_t)b * N * P + (cb + c_l);
  #pragma unroll
  for (int k = 0; k < 16; ++k){ int i = r0 + 64 * k; sc[sw(i)] = p[(size_t)i * P]; }
  __syncthreads();
  int g = tid >> 6, lane = tid & 63;
  fftq<1, 64>(s + g * SLOT, tw, lane);
  int c = cb + c_l;
  if (c < NH){
    const bool cpass = (c < 342);
    const float kyf = (float)c;
    const float FOUR_PI2 = 39.478417604357434f;
    #pragma unroll
    for (int k = 0; k < 16; ++k){
      int x = r0 + 64 * k;
      bool pass = cpass && (x < 341 || x >= 683);
      float2 F = pass ? sc[sw(x)] : make_float2(0.f, 0.f);
      size_t off = ((size_t)b * N + x) * P + c;
      float2 hv;
      if (first) hv = F;
      else { float2 ho = h[off]; hv = make_float2(F.x + beta * ho.x, F.y + beta * ho.y); }
      h[off] = hv;
      float kxf = (x < 512) ? (float)x : (float)(x - 1024);
      float lap = -FOUR_PI2 * (kxf * kxf + kyf * kyf);
      float lin = 1e-3f * lap - 0.1f;               // VISCOSITY*lap - DRAG
      float aa = 1.f + mu * lin;
      float dd = 1.f - mu * lin;
      float2 uv = u[off];
      u[off] = make_float2((uv.x * aa + gdt * hv.x) / dd,
                           (uv.y * aa + gdt * hv.y) / dd);
    }
  }
}

// pack outputs: [u.re, u.im, (u-vort).re/dt, (u-vort).im/dt]; padded->logical
__global__ __launch_bounds__(256) void finalize(const float2* __restrict__ u,
                                                const float2* __restrict__ vort,
                                                float* __restrict__ out){
  size_t pi = (size_t)blockIdx.x * 256 + threadIdx.x;
  if (pi >= PPLANE) return;
  int c = (int)(pi % P);
  if (c >= NH) return;
  size_t row = pi / P;
  size_t li = row * NH + c;
  float2 uv = u[pi], vv = vort[pi];
  out[li]              = uv.x;
  out[LPLANE + li]     = uv.y;
  out[2 * LPLANE + li] = (uv.x - vv.x) * 1000.f;   // /dt, dt=1e-3
  out[3 * LPLANE + li] = (uv.y - vv.y) * 1000.f;
}

extern "C" void kernel_launch(void* const* d_in, const int* in_sizes, int n_in,
                              void* d_out, int out_size, void* d_ws, size_t ws_size,
                              hipStream_t stream){
  const float* w0 = (const float*)d_in[0];
  float* out = (float*)d_out;
  char* ws = (char*)d_ws;

  const size_t CB = PPLANE * sizeof(float2);      // 34,078,720 bytes (padded field)
  // ws: tw + {vort, u, h, T2, T3, W1(=T0)} = 6*CB + 4KB ~= 204.5 MB
  size_t off = 0;
  float2* tw   = (float2*)(ws + off); off += 4096;
  float2* vort = (float2*)(ws + off); off += CB;
  float2* u    = (float2*)(ws + off); off += CB;
  float2* h    = (float2*)(ws + off); off += CB;
  float2* T2   = (float2*)(ws + off); off += CB;
  float2* T3   = (float2*)(ws + off); off += CB;
  float2* W1   = (float2*)(ws + off); off += CB;  // aliased: W1 == T0
  float2* T0   = W1;
  float2* T1   = (float2*)d_out;                  // padded T1 in d_out (34MB < 67MB), dead before finalize

  const double ALPHAS[6] = {0.0, 0.1496590219993, 0.3704009573644,
                            0.6222557631345, 0.9582821306748, 1.0};
  const double BETAS[5]  = {0.0, -0.4178904745, -1.192151694643,
                            -1.697784692471, -1.514183444257};
  const double GAMMAS[5] = {0.1496590219993, 0.3792103129999, 0.8229550293869,
                            0.6994504559488, 0.1530572479681};
  const double DT = 1e-3;

  hipLaunchKernelGGL(init_tw, dim3(2), dim3(256), 0, stream, tw);

  // forward rfft2 of w0; col_fwd writes vort AND u
  hipLaunchKernelGGL(row_r2c_pack, dim3(B * 512), dim3(256), 0, stream, w0, W1, tw);
  hipLaunchKernelGGL(col_fwd, dim3(B * 65), dim3(512), 0, stream, W1, vort, u, tw);

  for (int k = 0; k < 5; ++k){
    float gdt  = (float)(GAMMAS[k] * DT);
    float beta = (float)BETAS[k];
    float mu   = (float)(0.5 * DT * (ALPHAS[k + 1] - ALPHAS[k]));
    hipLaunchKernelGGL(spec_col_inv, dim3(B * 65, 4), dim3(512), 0, stream,
                       u, T0, T1, T2, T3, tw);
    hipLaunchKernelGGL(row_adv_fft, dim3(B * 512), dim3(256), 0, stream,
                       T0, T1, T2, T3, W1, tw);
    hipLaunchKernelGGL(col_fwd_update, dim3(B * 65), dim3(512), 0, stream,
                       W1, u, h, tw, gdt, beta, mu, (k == 0) ? 1 : 0);
  }

  hipLaunchKernelGGL(finalize, dim3((int)((PPLANE + 255) / 256)), dim3(256), 0, stream,
                     u, vort, out);
}

// Round 10
// 1325.157 us; speedup vs baseline: 1.8025x; 1.0422x over previous
//
#include <hip/hip_runtime.h>
#include <math.h>

static constexpr int N  = 1024;
static constexpr int NH = 513;        // logical spectral columns
static constexpr int P  = 520;        // padded pitch: 520*8B = 4160B % 64 == 0 (aligned segments)
static constexpr int B  = 8;
static constexpr size_t PPLANE = (size_t)B * N * P;    // padded complex elems per field
static constexpr size_t LPLANE = (size_t)B * N * NH;   // logical complex elems (output layout)
static constexpr int SLOT = 1089;     // per-column LDS stride in float2

__device__ __forceinline__ float2 cmul(float2 a, float2 b){
  return make_float2(a.x*b.x - a.y*b.y, a.x*b.y + a.y*b.x);
}
__device__ __forceinline__ int sw(int e){ return e + (e >> 4); }  // LDS anti-conflict swizzle, max 1086

// ---------------------------------------------------------------------------
// 1024-pt complex FFT in LDS, two radix-2 levels fused per pass (radix-4
// dataflow): 5 passes + bit-reversal = 6 barriers. Data index i lives at LDS
// slot sw(i). DIR=1 fwd e^{-i}, -1 inverse. Block-wide __syncthreads: all
// groups in a block run identical trip counts (threads with no work still
// reach every barrier). Twiddle identity: tw[k+256] = -i * tw[k].
// ---------------------------------------------------------------------------
template<int DIR, int GT>
__device__ void fftq(float2* s, const float2* __restrict__ tw, int lane){
  for (int i = lane; i < 1024; i += GT){
    int j = (int)(__brev((unsigned)i) >> 22);
    if (j > i){ float2 t = s[sw(i)]; s[sw(i)] = s[sw(j)]; s[sw(j)] = t; }
  }
  __syncthreads();
  #pragma unroll
  for (int st = 0; st < 10; st += 2){
    const int h = 1 << st;
    for (int q = lane; q < 256; q += GT){
      int j  = q & (h - 1);
      int g  = ((q >> st) << (st + 2)) | j;
      int i0 = sw(g), i1 = sw(g + h), i2 = sw(g + 2*h), i3 = sw(g + 3*h);
      float2 A = s[i0], Bv = s[i1], C = s[i2], D = s[i3];
      float2 w1 = tw[j << (9 - st)];
      float2 w2 = tw[j << (8 - st)];
      if (DIR < 0){ w1.y = -w1.y; w2.y = -w2.y; }
      float2 t1 = cmul(w1, Bv);
      float2 A1 = make_float2(A.x + t1.x, A.y + t1.y);
      float2 B1 = make_float2(A.x - t1.x, A.y - t1.y);
      float2 t2 = cmul(w1, D);
      float2 C1 = make_float2(C.x + t2.x, C.y + t2.y);
      float2 D1 = make_float2(C.x - t2.x, C.y - t2.y);
      float2 t3 = cmul(w2, C1);
      float2 t4c = cmul(w2, D1);
      float2 t4 = (DIR > 0) ? make_float2(t4c.y, -t4c.x) : make_float2(-t4c.y, t4c.x);
      s[i0] = make_float2(A1.x + t3.x, A1.y + t3.y);
      s[i2] = make_float2(A1.x - t3.x, A1.y - t3.y);
      s[i1] = make_float2(B1.x + t4.x, B1.y + t4.y);
      s[i3] = make_float2(B1.x - t4.x, B1.y - t4.y);
    }
    __syncthreads();
  }
}

// twiddle table: tw[k] = exp(-2*pi*i*k/1024), k in [0,512)
__global__ __launch_bounds__(256) void init_tw(float2* tw){
  int i = blockIdx.x * 256 + threadIdx.x;
  if (i < 512){
    double ang = -2.0 * M_PI * (double)i / 1024.0;
    tw[i] = make_float2((float)cos(ang), (float)sin(ang));
  }
}

// ---------------------------------------------------------------------------
// Packed row r2c (initial rfft2 of w0): TWO real rows as z = a + i*b.
// ---------------------------------------------------------------------------
__global__ __launch_bounds__(256) void row_r2c_pack(const float* __restrict__ in,
                                                    float2* __restrict__ out,
                                                    const float2* __restrict__ tw){
  __shared__ float2 s[1088];
  const int tid = threadIdx.x;
  size_t pr = blockIdx.x;
  const float* p0 = in + pr * 2048;
  const float* p1 = p0 + 1024;
  for (int i = tid; i < 1024; i += 256) s[sw(i)] = make_float2(p0[i], p1[i]);
  __syncthreads();
  fftq<1, 256>(s, tw, tid);
  float2* q0 = out + (size_t)(2 * pr) * P;
  float2* q1 = q0 + P;
  for (int k = tid; k < NH; k += 256){
    float2 Zk = s[sw(k)];
    float2 Zm = s[sw((1024 - k) & 1023)];
    q0[k] = make_float2(0.5f * (Zk.x + Zm.x), 0.5f * (Zk.y - Zm.y));
    q1[k] = make_float2(0.5f * (Zk.y + Zm.y), 0.5f * (Zm.x - Zk.x));
  }
}

// ---------------------------------------------------------------------------
// Column forward FFT, 512 thr, 8 cols/block; dual-writes vort and u.
// ---------------------------------------------------------------------------
__global__ __launch_bounds__(512, 4) void col_fwd(const float2* __restrict__ in,
                                                  float2* __restrict__ out,
                                                  float2* __restrict__ out2,
                                                  const float2* __restrict__ tw){
  __shared__ float2 s[8 * SLOT];
  const int tid = threadIdx.x;
  int blk = blockIdx.x;                    // b*65 + cgrp
  int b = blk / 65, cb = (blk % 65) * 8;
  int c_l = tid & 7, r0 = tid >> 3;
  float2* sc = s + c_l * SLOT;
  const float2* p = in + (size_t)b * N * P + (cb + c_l);
  #pragma unroll
  for (int k = 0; k < 16; ++k){ int i = r0 + 64 * k; sc[sw(i)] = p[(size_t)i * P]; }
  __syncthreads();
  int g = tid >> 6, lane = tid & 63;       // 8 groups x 64 lanes
  fftq<1, 64>(s + g * SLOT, tw, lane);
  if (cb + c_l < NH){
    size_t base = (size_t)b * N * P + (cb + c_l);
    #pragma unroll
    for (int k = 0; k < 16; ++k){
      int i = r0 + 64 * k;
      float2 v = sc[sw(i)];
      out [base + (size_t)i * P] = v;
      out2[base + (size_t)i * P] = v;
    }
  }
}

// ---------------------------------------------------------------------------
// Per-stage spectral multiplier + inverse column FFT, one field per block.
// XCD-aware dispatch order: bid = chunk*32 + f*8 + pl -> a panel's 4 field
// blocks sit at dispatch offsets +0/+8/+16/+24, i.e. the SAME XCD slot under
// round-robin assignment, temporally adjacent -> u-panel reads hit that
// XCD's L2 (8 panels live = 512 KB << 4 MB). Round-6/9 layout had the 4
// readers 520 dispatches apart -> FETCH measured 4x u (132 MB).
// Fields: 0: vx_hat = i*(-2pi*ky/lap)*u   1: vy_hat = i*(2pi*kx/lap)*u
//         2: gx_hat = i*(2pi*kx)*u        3: gy_hat = i*(2pi*ky)*u
// ---------------------------------------------------------------------------
__global__ __launch_bounds__(512, 4) void spec_col_inv(const float2* __restrict__ u,
                                                       float2* __restrict__ T0,
                                                       float2* __restrict__ T1,
                                                       float2* __restrict__ T2,
                                                       float2* __restrict__ T3,
                                                       const float2* __restrict__ tw){
  __shared__ float2 s[8 * SLOT];
  const int tid = threadIdx.x;
  int bid = blockIdx.x;                    // 0..2079
  int chunk = bid >> 5;                    // 65 chunks of 8 panels
  int idx = bid & 31;
  int f = idx >> 3;                        // field 0..3
  int panel = chunk * 8 + (idx & 7);       // 0..519 = b*65 + cgrp
  int b = panel / 65, cb = (panel % 65) * 8;
  int c_l = tid & 7, r0 = tid >> 3;
  int c = cb + c_l;
  int cg = min(c, 512);
  float2* sc = s + c_l * SLOT;
  const float2* p = u + (size_t)b * N * P + cg;
  const float kyc = (float)cg;
  const bool zerocol = (c == 0);
  const float TWO_PI = 6.2831853071795864769f;
  const float FOUR_PI2 = 39.478417604357434f;
  #pragma unroll
  for (int k = 0; k < 16; ++k){
    int i = r0 + 64 * k;
    float kxf = (i < 512) ? (float)i : (float)(i - 1024);
    float lap = -FOUR_PI2 * (kxf * kxf + kyc * kyc);
    float lap_safe = (i == 0 && zerocol) ? 1.f : lap;
    float m;
    if      (f == 0) m = -TWO_PI * kyc / lap_safe;
    else if (f == 1) m =  TWO_PI * kxf / lap_safe;
    else if (f == 2) m =  TWO_PI * kxf;
    else             m =  TWO_PI * kyc;
    float2 uv = p[(size_t)i * P];
    sc[sw(i)] = make_float2(-m * uv.y, m * uv.x);
  }
  __syncthreads();
  int g = tid >> 6, lane = tid & 63;
  fftq<-1, 64>(s + g * SLOT, tw, lane);
  float2* q = (f == 0) ? T0 : (f == 1) ? T1 : (f == 2) ? T2 : T3;
  if (c < NH){
    size_t base = (size_t)b * N * P + c;
    #pragma unroll
    for (int k = 0; k < 16; ++k){
      int i = r0 + 64 * k;
      q[base + (size_t)i * P] = sc[sw(i)];
    }
  }
}

// ---------------------------------------------------------------------------
// FUSED row stage, Hermitian pair-packed along y. The FOUR inverse FFTs
// (2 rows x 2 packed pairs) are independent -> run them as 4 parallel
// 128-lane groups (serial chain: 5 FFTs -> 2). Slice u4 = r*2 + pair:
// pair0 = vx + i*gx, pair1 = vy + i*gy. After the inverse FFT the real/imag
// channels hold the two real fields; advr = -(vx*gx + vy*gy)/N^4. Then ONE
// 512-wide packed forward r2c of (adv0, adv1).
// numpy irfft IGNORES Im of bins ky=0 and 512 (gy_hat@512 is purely
// imaginary & huge) -> zero them so packed spectra are exactly Hermitian.
// W1 ALIASED to T0: block reads its T0 rows before writing the same W1 rows;
// rows disjoint across blocks -> safe.
// ---------------------------------------------------------------------------
__global__ __launch_bounds__(512) void row_adv_fft(const float2* __restrict__ T0,
                                                   const float2* __restrict__ T1,
                                                   const float2* __restrict__ T2,
                                                   const float2* __restrict__ T3,
                                                   float2* __restrict__ W1,
                                                   const float2* __restrict__ tw){
  __shared__ float2 s[4 * SLOT];           // 34848 B
  __shared__ float advr[2][1024];          //  8192 B
  const int tid = threadIdx.x;
  int blk = blockIdx.x;                    // b*512 + qr
  int b = blk >> 9, qr = blk & 511;
  const float inv_n4 = 9.094947017729282e-13f;  // (1/1024^2)^2
  const int u4 = tid >> 7, lane = tid & 127;    // 4 groups x 128 lanes
  const int r = u4 >> 1, pair = u4 & 1;
  size_t row_off = ((size_t)b * N + 2 * qr + r) * P;
  const float2* pa = (pair == 0 ? T0 : T1) + row_off;  // vx / vy
  const float2* pb = (pair == 0 ? T2 : T3) + row_off;  // gx / gy
  float2* sc = s + u4 * SLOT;
  for (int i = lane; i < 1024; i += 128){
    float2 A, Bv;
    if (i <= 512){
      A = pa[i]; Bv = pb[i];
      if (i == 0 || i == 512){ A.y = 0.f; Bv.y = 0.f; }  // realify DC/Nyquist
      sc[sw(i)] = make_float2(A.x - Bv.y, A.y + Bv.x);   // A + iB
    } else {
      int m = 1024 - i; A = pa[m]; Bv = pb[m];
      sc[sw(i)] = make_float2(A.x + Bv.y, Bv.x - A.y);   // conj(A) + i*conj(B)
    }
  }
  __syncthreads();
  fftq<-1, 128>(sc, tw, lane);             // all 4 slices in parallel
  // advection: slice 2r holds (vx,gx) in (.x,.y); slice 2r+1 holds (vy,gy)
  for (int t = tid; t < 2048; t += 512){
    int rr = t >> 10, i = t & 1023;
    float2 a0 = s[(2 * rr) * SLOT + sw(i)];
    float2 a1 = s[(2 * rr + 1) * SLOT + sw(i)];
    advr[rr][i] = -(a0.x * a0.y + a1.x * a1.y) * inv_n4;
  }
  __syncthreads();
  // packed forward r2c of the two adv rows (slice 0)
  for (int i = tid; i < 1024; i += 512) s[sw(i)] = make_float2(advr[0][i], advr[1][i]);
  __syncthreads();
  fftq<1, 512>(s, tw, tid);
  float2* q0 = W1 + ((size_t)b * N + 2 * qr) * P;
  float2* q1 = q0 + P;
  for (int k = tid; k < NH; k += 512){
    float2 Zk = s[sw(k)];
    float2 Zm = s[sw((1024 - k) & 1023)];
    q0[k] = make_float2(0.5f * (Zk.x + Zm.x), 0.5f * (Zk.y - Zm.y));
    q1[k] = make_float2(0.5f * (Zk.y + Zm.y), 0.5f * (Zm.x - Zk.x));
  }
}

// ---------------------------------------------------------------------------
// Column forward FFT of advection + dealias + h/u CN update.
// Dealias: cols c<342 pass (int(2/3*513)==342 exactly); rows x<341||x>=683.
// ---------------------------------------------------------------------------
__global__ __launch_bounds__(512, 4) void col_fwd_update(const float2* __restrict__ A,
                                                         float2* __restrict__ u,
                                                         float2* __restrict__ h,
                                                         const float2* __restrict__ tw,
                                                         float gdt, float beta, float mu,
                                                         int first){
  __shared__ float2 s[8 * SLOT];
  const int tid = threadIdx.x;
  int blk = blockIdx.x;                    // b*65 + cgrp
  int b = blk / 65, cb = (blk % 65) * 8;
  int c_l = tid & 7, r0 = tid >> 3;
  float2* sc = s + c_l * SLOT;
  const float2* p = A + (size_t)b * N * P + (cb + c_l);
  #pragma unroll
  for (int k = 0; k < 16; ++k){ int i = r0 + 64 * k; sc[sw(i)] = p[(size_t)i * P]; }
  __syncthreads();
  int g = tid >> 6, lane = tid & 63;
  fftq<1, 64>(s + g * SLOT, tw, lane);
  int c = cb + c_l;
  if (c < NH){
    const bool cpass = (c < 342);
    const float kyf = (float)c;
    const float FOUR_PI2 = 39.478417604357434f;
    #pragma unroll
    for (int k = 0; k < 16; ++k){
      int x = r0 + 64 * k;
      bool pass = cpass && (x < 341 || x >= 683);
      float2 F = pass ? sc[sw(x)] : make_float2(0.f, 0.f);
      size_t off = ((size_t)b * N + x) * P + c;
      float2 hv;
      if (first) hv = F;
      else { float2 ho = h[off]; hv = make_float2(F.x + beta * ho.x, F.y + beta * ho.y); }
      h[off] = hv;
      float kxf = (x < 512) ? (float)x : (float)(x - 1024);
      float lap = -FOUR_PI2 * (kxf * kxf + kyf * kyf);
      float lin = 1e-3f * lap - 0.1f;               // VISCOSITY*lap - DRAG
      float aa = 1.f + mu * lin;
      float dd = 1.f - mu * lin;
      float2 uv = u[off];
      u[off] = make_float2((uv.x * aa + gdt * hv.x) / dd,
                           (uv.y * aa + gdt * hv.y) / dd);
    }
  }
}

// pack outputs: [u.re, u.im, (u-vort).re/dt, (u-vort).im/dt]; padded->logical
__global__ __launch_bounds__(256) void finalize(const float2* __restrict__ u,
                                                const float2* __restrict__ vort,
                                                float* __restrict__ out){
  size_t pi = (size_t)blockIdx.x * 256 + threadIdx.x;
  if (pi >= PPLANE) return;
  int c = (int)(pi % P);
  if (c >= NH) return;
  size_t row = pi / P;
  size_t li = row * NH + c;
  float2 uv = u[pi], vv = vort[pi];
  out[li]              = uv.x;
  out[LPLANE + li]     = uv.y;
  out[2 * LPLANE + li] = (uv.x - vv.x) * 1000.f;   // /dt, dt=1e-3
  out[3 * LPLANE + li] = (uv.y - vv.y) * 1000.f;
}

extern "C" void kernel_launch(void* const* d_in, const int* in_sizes, int n_in,
                              void* d_out, int out_size, void* d_ws, size_t ws_size,
                              hipStream_t stream){
  const float* w0 = (const float*)d_in[0];
  float* out = (float*)d_out;
  char* ws = (char*)d_ws;

  const size_t CB = PPLANE * sizeof(float2);      // 34,078,720 bytes (padded field)
  // ws: tw + {vort, u, h, T2, T3, W1(=T0)} = 6*CB + 4KB ~= 204.5 MB
  size_t off = 0;
  float2* tw   = (float2*)(ws + off); off += 4096;
  float2* vort = (float2*)(ws + off); off += CB;
  float2* u    = (float2*)(ws + off); off += CB;
  float2* h    = (float2*)(ws + off); off += CB;
  float2* T2   = (float2*)(ws + off); off += CB;
  float2* T3   = (float2*)(ws + off); off += CB;
  float2* W1   = (float2*)(ws + off); off += CB;  // aliased: W1 == T0
  float2* T0   = W1;
  float2* T1   = (float2*)d_out;                  // padded T1 in d_out (34MB < 67MB), dead before finalize

  const double ALPHAS[6] = {0.0, 0.1496590219993, 0.3704009573644,
                            0.6222557631345, 0.9582821306748, 1.0};
  const double BETAS[5]  = {0.0, -0.4178904745, -1.192151694643,
                            -1.697784692471, -1.514183444257};
  const double GAMMAS[5] = {0.1496590219993, 0.3792103129999, 0.8229550293869,
                            0.6994504559488, 0.1530572479681};
  const double DT = 1e-3;

  hipLaunchKernelGGL(init_tw, dim3(2), dim3(256), 0, stream, tw);

  // forward rfft2 of w0; col_fwd writes vort AND u
  hipLaunchKernelGGL(row_r2c_pack, dim3(B * 512), dim3(256), 0, stream, w0, W1, tw);
  hipLaunchKernelGGL(col_fwd, dim3(B * 65), dim3(512), 0, stream, W1, vort, u, tw);

  for (int k = 0; k < 5; ++k){
    float gdt  = (float)(GAMMAS[k] * DT);
    float beta = (float)BETAS[k];
    float mu   = (float)(0.5 * DT * (ALPHAS[k + 1] - ALPHAS[k]));
    hipLaunchKernelGGL(spec_col_inv, dim3(65 * 32), dim3(512), 0, stream,
                       u, T0, T1, T2, T3, tw);
    hipLaunchKernelGGL(row_adv_fft, dim3(B * 512), dim3(512), 0, stream,
                       T0, T1, T2, T3, W1, tw);
    hipLaunchKernelGGL(col_fwd_update, dim3(B * 65), dim3(512), 0, stream,
                       W1, u, h, tw, gdt, beta, mu, (k == 0) ? 1 : 0);
  }

  hipLaunchKernelGGL(finalize, dim3((int)((PPLANE + 255) / 256)), dim3(256), 0, stream,
                     u, vort, out);
}